// Round 24
// baseline (51.862 us; speedup 1.0000x reference)
//
#include <hip/hip_runtime.h>
#include <math.h>

#define N  2048
#define K  8
#define NK 1024
#define R  4             // rows per block (proven optimum)
#define TPB 512
#define WSEG 264         // 260 data floats + zero slot @260 (+3 pad), 16B-divisible
#define ZSLOT 260
#define TAU_C 0.5f
#define TAU_S 0.5f

// Barrier-free wave-private staging (replay-safe single-kernel class, R8-R23).
// Key fact: idx[k] is sorted, so the positions of the members of a 256-column
// window are CONTIGUOUS (length <= 256). Each wave stages its own per-client
// segment [lb4, lb4+260) into a private LDS slice and gathers wave-locally:
// the row loop has ZERO block barriers (R18 had 2 per row -> 16-wave convoy).
// lb4 (aligned, clamped) and local gather indices qv are window-only -> hoisted.
// Math is byte-identical to R18 (19.6us, absmax 0.0, 6x-validated).
__global__ void __launch_bounds__(TPB, 4)
fia_fused(const float* __restrict__ adj,
          const int*   __restrict__ idx,
          float* __restrict__ out) {
    __shared__ union {
        short jj[K][N];                  // 32 KB: pos of y in idx[k]; dead after hoist
        float ws[8][K][WSEG];            // 67.6 KB: wave-private stage slices
    } u;
    __shared__ short  ixs[K][R];         // pos of row x in idx[k], or -1
    __shared__ float  lutCS[81];         // exact IEEE cs/n (ref C bits)
    __shared__ float2 lutB[81];          // (BloN, BhiN) decision bounds on vs
    __shared__ float  lutR[16];          // 1/max(cnt,1e-5)

    const int tid  = threadIdx.x;
    const int lane = tid & 63;
    const int wid  = tid >> 6;           // wave id 0..7
    const int X0   = blockIdx.x * R;

    // ---- one-time init: jj=-1, ixs=-1, LUTs
    {
        int4  m1 = make_int4(-1, -1, -1, -1);
        int4* p4 = (int4*)&u.jj[0][0];               // 2048 int4
        #pragma unroll
        for (int q = 0; q < (K * N * 2) / (16 * TPB); ++q)   // 4
            p4[q * TPB + tid] = m1;
        if (tid < K * R) ((short*)ixs)[tid] = (short)-1;
        if (tid < 16) lutR[tid] = 1.0f / fmaxf((float)tid, 1e-5f);
        if (tid < 81) {
            int cn = tid / 9, cc = tid % 9;
            float nn = fmaxf((float)cn, 1e-5f);
            float C  = (float)cc / nn;               // IEEE divide == ref C bits
            lutCS[tid] = C;
            float lo, hi;
            if (2 * cc <= cn) { lo = -2.0f; hi = -1.0f; }    // always reject
            else {
                float B = logf(2.0f * C);            // V boundary: S = 0.5
                float d = 1e-3f * (1.0f + fabsf(B)); // >=100x all err sources
                lo = (B - d) * (float)cn;
                hi = (B + d) * (float)cn;
            }
            lutB[tid] = make_float2(lo, hi);
        }
    }
    __syncthreads();

    // ---- scan idx: int4 loads (R16-proven). Unique writer per cell.
    #pragma unroll
    for (int it = 0; it < (K * NK) / (4 * TPB); ++it) {      // 4
        int  t4   = it * TPB + tid;
        int4 w    = ((const int4*)idx)[t4];          // coalesced 16B
        int  base = t4 * 4;
        int  k    = base >> 10;
        int  p    = base & (NK - 1);
        u.jj[k][w.x] = (short)(p);
        u.jj[k][w.y] = (short)(p + 1);
        u.jj[k][w.z] = (short)(p + 2);
        u.jj[k][w.w] = (short)(p + 3);
        int r0 = w.x - X0, r1 = w.y - X0, r2 = w.z - X0, r3 = w.w - X0;
        if ((unsigned)r0 < (unsigned)R) ixs[k][r0] = (short)(p);
        if ((unsigned)r1 < (unsigned)R) ixs[k][r1] = (short)(p + 1);
        if ((unsigned)r2 < (unsigned)R) ixs[k][r2] = (short)(p + 2);
        if ((unsigned)r3 < (unsigned)R) ixs[k][r3] = (short)(p + 3);
    }
    __syncthreads();

    // ---- hoist per-thread raw positions from jj (LAST use of jj)
    const int y0 = tid * 4;                          // 4 consecutive columns
    int jraw[K][4];
    int jmask[4] = {0, 0, 0, 0};
    #pragma unroll
    for (int k = 0; k < K; ++k) {
        short4 v = *(const short4*)&u.jj[k][y0];     // ds_read_b64
        jraw[k][0] = v.x; jraw[k][1] = v.y; jraw[k][2] = v.z; jraw[k][3] = v.w;
        jmask[0] |= (v.x >= 0) ? (1 << k) : 0;
        jmask[1] |= (v.y >= 0) ? (1 << k) : 0;
        jmask[2] |= (v.z >= 0) ? (1 << k) : 0;
        jmask[3] |= (v.w >= 0) ? (1 << k) : 0;
    }

    // ---- per-wave segment bases (window-only -> hoisted) + local indices
    int lbs[K];                                      // wave-uniform, in SGPRs
    int qv[K][4];                                    // local gather idx or ZSLOT
    #pragma unroll
    for (int k = 0; k < K; ++k) {
        int mn = 0x7fffffff;
        #pragma unroll
        for (int yy = 0; yy < 4; ++yy)
            mn = min(mn, jraw[k][yy] >= 0 ? jraw[k][yy] : 0x7fffffff);
        #pragma unroll
        for (int s = 1; s < 64; s <<= 1)             // wave-min, 6 steps
            mn = min(mn, __shfl_xor(mn, s));
        int lb = mn & ~3;                            // 4-align down
        lb = (lb > NK - WSEG + 4) ? (NK - WSEG + 4) : lb;   // 764: stay in-bounds
        lbs[k] = __builtin_amdgcn_readfirstlane(lb);
        // present: q = jraw - lb in [0, 258] (contiguity: hi-lo <= 255, align -3,
        // end-clamp covers lo>=768). absent: zero slot.
        #pragma unroll
        for (int yy = 0; yy < 4; ++yy)
            qv[k][yy] = jraw[k][yy] >= 0 ? jraw[k][yy] - lbs[k] : ZSLOT;
    }
    __syncthreads();                                 // jj dead -> ws writable (LAST barrier)

    // zero slot per wave-client slice (wave-private; never overwritten)
    if (lane < K) u.ws[wid][lane][ZSLOT] = 0.0f;

    // ---- row loop: NO block barriers. Wave-private stage -> gather -> stats.
    #pragma unroll 1
    for (int r = 0; r < R; ++r) {
        int kp = 0;
        int ixr[K];
        #pragma unroll
        for (int k = 0; k < K; ++k) {
            int v = (int)ixs[k][r];                  // uniform LDS read
            ixr[k] = __builtin_amdgcn_readfirstlane(v);
            kp |= (ixr[k] >= 0) ? (1 << k) : 0;
        }

        // STAGE: per client, 64 lanes x dwordx4 cover [lb, lb+256);
        // lane 0 adds [lb+256, lb+260). All in-bounds (lb <= 764).
        float4 v4[K];
        float4 vt[K];
        #pragma unroll
        for (int k = 0; k < K; ++k) {
            if ((kp >> k) & 1) {                     // SGPR branch
                const float* rowg =
                    adj + ((size_t)k * NK + (size_t)ixr[k]) * NK + lbs[k];
                v4[k] = ((const float4*)rowg)[lane];         // coalesced 16B
                if (lane == 0) vt[k] = ((const float4*)rowg)[64];
            }
        }
        #pragma unroll
        for (int k = 0; k < K; ++k) {
            if ((kp >> k) & 1) {
                ((float4*)&u.ws[wid][k][0])[lane] = v4[k];   // ds_write_b128
                if (lane == 0) ((float4*)&u.ws[wid][k][0])[64] = vt[k];
            }
        }

        // PASS A: wave-local gather + {sum, sumsq, cs}; select-free (zero slot).
        float sum[4]   = {0.f, 0.f, 0.f, 0.f};
        float sumsq[4] = {0.f, 0.f, 0.f, 0.f};
        int   csi[4]   = {0, 0, 0, 0};
        #pragma unroll
        for (int k = 0; k < K; ++k) {
            if ((kp >> k) & 1) {                     // SGPR branch
                #pragma unroll
                for (int yy = 0; yy < 4; ++yy) {
                    float a = u.ws[wid][k][qv[k][yy]];   // ds_read_b32
                    sum[yy]   += a;                  // +0.0 for absent == ref
                    sumsq[yy]  = fmaf(a, a, sumsq[yy]);
                    csi[yy]   += (a > TAU_C) ? 1 : 0;
                }
            }
        }

        // PASS B: thin decision path; rare in-band -> byte-exact fallback.
        float res[4];
        #pragma unroll
        for (int yy = 0; yy < 4; ++yy) {
            const int m   = jmask[yy] & kp;
            const int cnt = __popc(m);
            const float cf = (float)cnt;
            float mean = sum[yy] * lutR[cnt];        // exact for cnt=1,2,4,8
            float t    = fmaf(cf, mean, -2.0f * sum[yy]);
            float vsf  = fmaf(mean, t, sumsq[yy]);   // ~vs, |err| <~1e-5

            const int li = cnt * 9 + csi[yy];
            float2 bb = lutB[li];
            float rr;
            if (__builtin_expect(vsf >= bb.x && vsf <= bb.y, 0)) {
                // in-band (~0.5%): byte-exact reference sequence, re-gather.
                float n      = fmaxf(cf, 1e-5f);
                float mean_e = sum[yy] / n;          // IEEE divide (ref bits)
                float vs = 0.f;
                #pragma unroll
                for (int k = 0; k < K; ++k) {
                    if ((kp >> k) & 1) {
                        bool  p = (m >> k) & 1;
                        float a = u.ws[wid][k][qv[k][yy]];
                        float d = a - mean_e;
                        vs += p ? d * d : 0.f;       // select blocks fma-fuse
                    }
                }
                float C = lutCS[li];                 // == cs/n, same IEEE bits
                float V = vs / n;                    // IEEE divide
                float S = C * expf(-V);              // precise expf
                rr = (S > TAU_S && cnt > 0) ? mean_e : 0.f;
            } else {
                rr = (vsf < bb.x) ? mean : 0.f;      // certain accept / reject
            }
            res[yy] = rr;
        }

        float4 o;
        o.x = res[0]; o.y = res[1]; o.z = res[2]; o.w = res[3];
        *(float4*)(out + (size_t)(X0 + r) * N + y0) = o;
    }
}

extern "C" void kernel_launch(void* const* d_in, const int* in_sizes, int n_in,
                              void* d_out, int out_size, void* d_ws, size_t ws_size,
                              hipStream_t stream) {
    const float* adj = (const float*)d_in[0];        // (K, NK, NK) f32
    const int*   idx = (const int*)d_in[1];          // (K, NK) i32
    float*       out = (float*)d_out;                // (N, N) f32

    dim3 block(TPB, 1, 1);
    dim3 grid(N / R, 1, 1);                          // 512 blocks x 4 rows
    fia_fused<<<grid, block, 0, stream>>>(adj, idx, out);
}

// Round 25
// 19.615 us; speedup vs baseline: 2.6441x; 2.6441x over previous
//
#include <hip/hip_runtime.h>
#include <math.h>

#define N  2048
#define K  8
#define NK 1024
#define R  4             // rows per block (proven optimum: R18 vs R20/R21)
#define TPB 512
#define SLOT NK          // zero slot index in stage rows
#define TAU_C 0.5f
#define TAU_S 0.5f

// FINAL (R18, the measured optimum: 19.6us, absmax 0.0, reproduced 2x).
// Single fused kernel (replay-safe class, R8-R24): block rebuilds index maps
// from the immutable `idx` into LDS, then serves R=4 full output rows.
//  - PASS A accumulates sum, sumsq (fma), cs -- select-free via zero slot
//  - vs via identity vs = sumsq + mean*(cnt*mean - 2*sum)  (err <~1e-5,
//    100x inside the lutB decision band -> decisions provably exact)
//  - mean via reciprocal LUT (bit-exact for cnt in {1,2,4,8}; <=2ulp else)
//  - S>0.5 decision via conservative precomputed bounds on vs; in-band cells
//    (~0.5%) re-gather and run the byte-exact reference sequence
__global__ void __launch_bounds__(TPB, 4)
fia_fused(const float* __restrict__ adj,
          const int*   __restrict__ idx,
          float* __restrict__ out) {
    __shared__ short  jj[K][N];          // 32 KB: pos of y in idx[k], or -1
    __shared__ short  ixs[K][R];         // pos of row x in idx[k], or -1
    __shared__ float  stage[K][NK + 4];  // 32.9 KB: row data + zero slot
    __shared__ float  lutCS[81];         // exact IEEE cs/n (ref C bits)
    __shared__ float2 lutB[81];          // (BloN, BhiN) decision bounds on vs
    __shared__ float  lutR[16];          // 1/max(cnt,1e-5)

    const int tid = threadIdx.x;
    const int X0  = blockIdx.x * R;

    // ---- one-time init: maps to -1, zero slots, LUTs
    {
        int4  m1 = make_int4(-1, -1, -1, -1);
        int4* p4 = (int4*)&jj[0][0];                 // 2048 int4
        #pragma unroll
        for (int q = 0; q < (K * N * 2) / (16 * TPB); ++q)   // 4
            p4[q * TPB + tid] = m1;
        if (tid < K * R) ((short*)ixs)[tid] = (short)-1;
        if (tid < K) stage[tid][SLOT] = 0.0f;        // zero slot per client
        if (tid < 16) lutR[tid] = 1.0f / fmaxf((float)tid, 1e-5f);
        if (tid < 81) {
            int cn = tid / 9, cc = tid % 9;
            float nn = fmaxf((float)cn, 1e-5f);
            float C  = (float)cc / nn;               // IEEE divide == ref C bits
            lutCS[tid] = C;
            float lo, hi;
            if (2 * cc <= cn) { lo = -2.0f; hi = -1.0f; }    // always reject
            else {
                float B = logf(2.0f * C);            // V boundary: S = 0.5
                float d = 1e-3f * (1.0f + fabsf(B)); // >=100x all err sources
                lo = (B - d) * (float)cn;
                hi = (B + d) * (float)cn;
            }
            lutB[tid] = make_float2(lo, hi);
        }
    }
    __syncthreads();

    // ---- scan idx: int4 loads (R16-proven). Unique writer per cell.
    #pragma unroll
    for (int it = 0; it < (K * NK) / (4 * TPB); ++it) {      // 4
        int  t4   = it * TPB + tid;
        int4 w    = ((const int4*)idx)[t4];          // coalesced 16B
        int  base = t4 * 4;
        int  k    = base >> 10;
        int  p    = base & (NK - 1);
        jj[k][w.x] = (short)(p);
        jj[k][w.y] = (short)(p + 1);
        jj[k][w.z] = (short)(p + 2);
        jj[k][w.w] = (short)(p + 3);
        int r0 = w.x - X0, r1 = w.y - X0, r2 = w.z - X0, r3 = w.w - X0;
        if ((unsigned)r0 < (unsigned)R) ixs[k][r0] = (short)(p);
        if ((unsigned)r1 < (unsigned)R) ixs[k][r1] = (short)(p + 1);
        if ((unsigned)r2 < (unsigned)R) ixs[k][r2] = (short)(p + 2);
        if ((unsigned)r3 < (unsigned)R) ixs[k][r3] = (short)(p + 3);
    }
    __syncthreads();

    // ---- hoisted per-thread column state (reused by all R rows)
    const int y0 = tid * 4;                          // 4 consecutive columns
    int jc[K][4];                                    // gather index or SLOT
    int jmask[4] = {0, 0, 0, 0};
    #pragma unroll
    for (int k = 0; k < K; ++k) {
        short4 v = *(const short4*)&jj[k][y0];       // ds_read_b64
        int j0 = v.x, j1 = v.y, j2 = v.z, j3 = v.w;
        jmask[0] |= (j0 >= 0) ? (1 << k) : 0;
        jmask[1] |= (j1 >= 0) ? (1 << k) : 0;
        jmask[2] |= (j2 >= 0) ? (1 << k) : 0;
        jmask[3] |= (j3 >= 0) ? (1 << k) : 0;
        jc[k][0] = (j0 >= 0) ? j0 : SLOT;            // absent -> zero slot
        jc[k][1] = (j1 >= 0) ? j1 : SLOT;
        jc[k][2] = (j2 >= 0) ? j2 : SLOT;
        jc[k][3] = (j3 >= 0) ? j3 : SLOT;
    }

    // ---- row loop (R13/R16/R18-proven staging schedule)
    #pragma unroll 1
    for (int r = 0; r < R; ++r) {
        int kp = 0;
        int ixr[K];
        #pragma unroll
        for (int k = 0; k < K; ++k) {
            int v = (int)ixs[k][r];                  // uniform LDS read
            ixr[k] = __builtin_amdgcn_readfirstlane(v);
            kp |= (ixr[k] >= 0) ? (1 << k) : 0;
        }

        // STAGE loads first (overlap with other waves' prior-row stats)
        float2 sr[K];
        #pragma unroll
        for (int k = 0; k < K; ++k) {
            if (ixr[k] >= 0) {                       // scalar branch
                const float2* __restrict__ src =
                    (const float2*)(adj + ((size_t)k * NK + (size_t)ixr[k]) * NK);
                sr[k] = src[tid];                    // fully coalesced 8B
            }
        }
        __syncthreads();                             // WAR: prev row done w/ stage
        #pragma unroll
        for (int k = 0; k < K; ++k) {
            if (ixr[k] >= 0)
                ((float2*)&stage[k][0])[tid] = sr[k];   // ds_write_b64
        }
        __syncthreads();                             // stage visible

        // PASS A: gather + {sum, sumsq, cs}, scalar-gated; select-free.
        float sum[4]   = {0.f, 0.f, 0.f, 0.f};
        float sumsq[4] = {0.f, 0.f, 0.f, 0.f};
        int   csi[4]   = {0, 0, 0, 0};
        #pragma unroll
        for (int k = 0; k < K; ++k) {
            if ((kp >> k) & 1) {                     // SGPR branch
                #pragma unroll
                for (int yy = 0; yy < 4; ++yy) {
                    float a = stage[k][jc[k][yy]];   // ds_read_b32
                    sum[yy]   += a;                  // +0.0 for absent == ref
                    sumsq[yy]  = fmaf(a, a, sumsq[yy]);
                    csi[yy]   += (a > TAU_C) ? 1 : 0;
                }
            }
        }

        // PASS B: thin decision path; rare in-band -> byte-exact fallback.
        float res[4];
        #pragma unroll
        for (int yy = 0; yy < 4; ++yy) {
            const int m   = jmask[yy] & kp;
            const int cnt = __popc(m);
            const float cf = (float)cnt;
            float mean = sum[yy] * lutR[cnt];        // exact for cnt=1,2,4,8
            float t    = fmaf(cf, mean, -2.0f * sum[yy]);
            float vsf  = fmaf(mean, t, sumsq[yy]);   // ~vs, |err| <~1e-5

            const int li = cnt * 9 + csi[yy];
            float2 bb = lutB[li];
            float rr;
            if (__builtin_expect(vsf >= bb.x && vsf <= bb.y, 0)) {
                // in-band (~0.5%): byte-exact reference sequence, re-gather.
                float n      = fmaxf(cf, 1e-5f);
                float mean_e = sum[yy] / n;          // IEEE divide (ref bits)
                float vs = 0.f;
                #pragma unroll
                for (int k = 0; k < K; ++k) {
                    if ((kp >> k) & 1) {
                        bool  p = (m >> k) & 1;
                        float a = stage[k][jc[k][yy]];
                        float d = a - mean_e;
                        vs += p ? d * d : 0.f;       // select blocks fma-fuse
                    }
                }
                float C = lutCS[li];                 // == cs/n, same IEEE bits
                float V = vs / n;                    // IEEE divide
                float S = C * expf(-V);              // precise expf
                rr = (S > TAU_S && cnt > 0) ? mean_e : 0.f;
            } else {
                rr = (vsf < bb.x) ? mean : 0.f;      // certain accept / reject
            }
            res[yy] = rr;
        }

        float4 o;
        o.x = res[0]; o.y = res[1]; o.z = res[2]; o.w = res[3];
        *(float4*)(out + (size_t)(X0 + r) * N + y0) = o;
    }
}

extern "C" void kernel_launch(void* const* d_in, const int* in_sizes, int n_in,
                              void* d_out, int out_size, void* d_ws, size_t ws_size,
                              hipStream_t stream) {
    const float* adj = (const float*)d_in[0];        // (K, NK, NK) f32
    const int*   idx = (const int*)d_in[1];          // (K, NK) i32
    float*       out = (float*)d_out;                // (N, N) f32

    dim3 block(TPB, 1, 1);
    dim3 grid(N / R, 1, 1);                          // 512 blocks x 4 rows
    fia_fused<<<grid, block, 0, stream>>>(adj, idx, out);
}

// Round 26
// 19.104 us; speedup vs baseline: 2.7147x; 1.0267x over previous
//
#include <hip/hip_runtime.h>
#include <math.h>

#define N  2048
#define K  8
#define NK 1024
#define R  4             // rows per block (proven optimum)
#define TPB 512
#define SLOT NK          // zero slot index in stage rows
#define TAU_C 0.5f
#define TAU_S 0.5f

// Single fused kernel (replay-safe class, R8-R25). R18 body/math (19.6us,
// absmax 0.0, 3x reproduced) with ONE change: stage granularity 1 row -> 2
// rows per barrier episode. Both rows' loads are issued back-to-back and one
// vmcnt drain + barrier pair covers them -> 4 barrier pairs/block -> 2.
// Schedule SHAPE is unchanged (loads->barrier->write->barrier->compute; no
// cross-PASS pipelining, which is what sank R19). st[2] unions the
// dead-after-hoist jj map (union proven R21) -> ~67KB LDS, 2 blocks/CU.

// PASS A+B for one row from stage buffer BUF (R18-proven exact-band math).
#define ROW_PASS(rr, kpX, BUF)                                                 \
    {                                                                          \
        float sum[4]   = {0.f, 0.f, 0.f, 0.f};                                 \
        float sumsq[4] = {0.f, 0.f, 0.f, 0.f};                                 \
        int   csi[4]   = {0, 0, 0, 0};                                         \
        _Pragma("unroll")                                                      \
        for (int k = 0; k < K; ++k) {                                          \
            if ((kpX >> k) & 1) {                    /* SGPR branch */         \
                _Pragma("unroll")                                              \
                for (int yy = 0; yy < 4; ++yy) {                               \
                    float a = BUF[k][jc[k][yy]];     /* ds_read_b32 */         \
                    sum[yy]   += a;                  /* +0.0 absent == ref */  \
                    sumsq[yy]  = fmaf(a, a, sumsq[yy]);                        \
                    csi[yy]   += (a > TAU_C) ? 1 : 0;                          \
                }                                                              \
            }                                                                  \
        }                                                                      \
        float res[4];                                                          \
        _Pragma("unroll")                                                      \
        for (int yy = 0; yy < 4; ++yy) {                                       \
            const int m   = jmask[yy] & kpX;                                   \
            const int cnt = __popc(m);                                         \
            const float cf = (float)cnt;                                       \
            float mean = sum[yy] * lutR[cnt];        /* exact cnt=1,2,4,8 */   \
            float t    = fmaf(cf, mean, -2.0f * sum[yy]);                      \
            float vsf  = fmaf(mean, t, sumsq[yy]);   /* ~vs, err <~1e-5 */     \
            const int li = cnt * 9 + csi[yy];                                  \
            float2 bb = lutB[li];                                              \
            float rr_;                                                         \
            if (__builtin_expect(vsf >= bb.x && vsf <= bb.y, 0)) {             \
                /* in-band (~0.5%): byte-exact reference sequence */           \
                float n      = fmaxf(cf, 1e-5f);                               \
                float mean_e = sum[yy] / n;          /* IEEE divide */         \
                float vs = 0.f;                                                \
                _Pragma("unroll")                                              \
                for (int k = 0; k < K; ++k) {                                  \
                    if ((kpX >> k) & 1) {                                      \
                        bool  p = (m >> k) & 1;                                \
                        float a = BUF[k][jc[k][yy]];                           \
                        float d = a - mean_e;                                  \
                        vs += p ? d * d : 0.f;       /* select blocks fma */   \
                    }                                                          \
                }                                                              \
                float C = lutCS[li];                 /* == cs/n, ref bits */   \
                float V = vs / n;                    /* IEEE divide */         \
                float S = C * expf(-V);              /* precise expf */        \
                rr_ = (S > TAU_S && cnt > 0) ? mean_e : 0.f;                   \
            } else {                                                           \
                rr_ = (vsf < bb.x) ? mean : 0.f;     /* certain acc/rej */     \
            }                                                                  \
            res[yy] = rr_;                                                     \
        }                                                                      \
        float4 o_;                                                             \
        o_.x = res[0]; o_.y = res[1]; o_.z = res[2]; o_.w = res[3];            \
        *(float4*)(out + (size_t)(X0 + (rr)) * N + y0) = o_;                   \
    }

__global__ void __launch_bounds__(TPB, 4)
fia_fused(const float* __restrict__ adj,
          const int*   __restrict__ idx,
          float* __restrict__ out) {
    __shared__ union {
        short jj[K][N];                  // 32 KB: pos of y in idx[k]; dead after hoist
        float st[2][K][NK + 4];          // 65.8 KB: 2-row stage + zero slots
    } u;
    __shared__ short  ixs[K][R];         // pos of row x in idx[k], or -1
    __shared__ float  lutCS[81];         // exact IEEE cs/n (ref C bits)
    __shared__ float2 lutB[81];          // (BloN, BhiN) decision bounds on vs
    __shared__ float  lutR[16];          // 1/max(cnt,1e-5)

    const int tid = threadIdx.x;
    const int X0  = blockIdx.x * R;

    // ---- one-time init: jj=-1, ixs=-1, LUTs
    {
        int4  m1 = make_int4(-1, -1, -1, -1);
        int4* p4 = (int4*)&u.jj[0][0];               // 2048 int4
        #pragma unroll
        for (int q = 0; q < (K * N * 2) / (16 * TPB); ++q)   // 4
            p4[q * TPB + tid] = m1;
        if (tid < K * R) ((short*)ixs)[tid] = (short)-1;
        if (tid < 16) lutR[tid] = 1.0f / fmaxf((float)tid, 1e-5f);
        if (tid < 81) {
            int cn = tid / 9, cc = tid % 9;
            float nn = fmaxf((float)cn, 1e-5f);
            float C  = (float)cc / nn;               // IEEE divide == ref C bits
            lutCS[tid] = C;
            float lo, hi;
            if (2 * cc <= cn) { lo = -2.0f; hi = -1.0f; }    // always reject
            else {
                float B = logf(2.0f * C);            // V boundary: S = 0.5
                float d = 1e-3f * (1.0f + fabsf(B)); // >=100x all err sources
                lo = (B - d) * (float)cn;
                hi = (B + d) * (float)cn;
            }
            lutB[tid] = make_float2(lo, hi);
        }
    }
    __syncthreads();

    // ---- scan idx: int4 loads (R16-proven). Unique writer per cell.
    #pragma unroll
    for (int it = 0; it < (K * NK) / (4 * TPB); ++it) {      // 4
        int  t4   = it * TPB + tid;
        int4 w    = ((const int4*)idx)[t4];          // coalesced 16B
        int  base = t4 * 4;
        int  k    = base >> 10;
        int  p    = base & (NK - 1);
        u.jj[k][w.x] = (short)(p);
        u.jj[k][w.y] = (short)(p + 1);
        u.jj[k][w.z] = (short)(p + 2);
        u.jj[k][w.w] = (short)(p + 3);
        int r0 = w.x - X0, r1 = w.y - X0, r2 = w.z - X0, r3 = w.w - X0;
        if ((unsigned)r0 < (unsigned)R) ixs[k][r0] = (short)(p);
        if ((unsigned)r1 < (unsigned)R) ixs[k][r1] = (short)(p + 1);
        if ((unsigned)r2 < (unsigned)R) ixs[k][r2] = (short)(p + 2);
        if ((unsigned)r3 < (unsigned)R) ixs[k][r3] = (short)(p + 3);
    }
    __syncthreads();

    // ---- hoist per-thread column state from jj (LAST use of jj)
    const int y0 = tid * 4;                          // 4 consecutive columns
    int jc[K][4];                                    // gather index or SLOT
    int jmask[4] = {0, 0, 0, 0};
    #pragma unroll
    for (int k = 0; k < K; ++k) {
        short4 v = *(const short4*)&u.jj[k][y0];     // ds_read_b64
        int j0 = v.x, j1 = v.y, j2 = v.z, j3 = v.w;
        jmask[0] |= (j0 >= 0) ? (1 << k) : 0;
        jmask[1] |= (j1 >= 0) ? (1 << k) : 0;
        jmask[2] |= (j2 >= 0) ? (1 << k) : 0;
        jmask[3] |= (j3 >= 0) ? (1 << k) : 0;
        jc[k][0] = (j0 >= 0) ? j0 : SLOT;            // absent -> zero slot
        jc[k][1] = (j1 >= 0) ? j1 : SLOT;
        jc[k][2] = (j2 >= 0) ? j2 : SLOT;
        jc[k][3] = (j3 >= 0) ? j3 : SLOT;
    }
    __syncthreads();                                 // jj dead; st writable

    // ---- zero slots for both stage buffers (never touched by stage writes)
    if (tid < K)          u.st[0][tid][SLOT] = 0.0f;
    else if (tid < 2 * K) u.st[1][tid - K][SLOT] = 0.0f;

    // ---- row-PAIR loop: 2 rows per barrier episode (R18 shape, half episodes)
    #pragma unroll 1
    for (int rp = 0; rp < R; rp += 2) {
        int kpA = 0, kpB = 0;
        int ixrA[K], ixrB[K];
        #pragma unroll
        for (int k = 0; k < K; ++k) {
            int vA = (int)ixs[k][rp];                // uniform LDS reads
            int vB = (int)ixs[k][rp + 1];
            ixrA[k] = __builtin_amdgcn_readfirstlane(vA);
            ixrB[k] = __builtin_amdgcn_readfirstlane(vB);
            kpA |= (ixrA[k] >= 0) ? (1 << k) : 0;
            kpB |= (ixrB[k] >= 0) ? (1 << k) : 0;
        }

        // STAGE loads for BOTH rows, issued back-to-back (one latency episode)
        float2 srA[K], srB[K];
        #pragma unroll
        for (int k = 0; k < K; ++k) {
            if (ixrA[k] >= 0) {                      // scalar branch
                const float2* __restrict__ src =
                    (const float2*)(adj + ((size_t)k * NK + (size_t)ixrA[k]) * NK);
                srA[k] = src[tid];                   // coalesced 8B
            }
        }
        #pragma unroll
        for (int k = 0; k < K; ++k) {
            if (ixrB[k] >= 0) {
                const float2* __restrict__ src =
                    (const float2*)(adj + ((size_t)k * NK + (size_t)ixrB[k]) * NK);
                srB[k] = src[tid];                   // coalesced 8B
            }
        }
        __syncthreads();                             // WAR: prev pair done w/ st
        #pragma unroll
        for (int k = 0; k < K; ++k) {
            if (ixrA[k] >= 0)
                ((float2*)&u.st[0][k][0])[tid] = srA[k];    // ds_write_b64
        }
        #pragma unroll
        for (int k = 0; k < K; ++k) {
            if (ixrB[k] >= 0)
                ((float2*)&u.st[1][k][0])[tid] = srB[k];
        }
        __syncthreads();                             // both rows visible

        ROW_PASS(rp,     kpA, u.st[0])
        ROW_PASS(rp + 1, kpB, u.st[1])
    }
}

extern "C" void kernel_launch(void* const* d_in, const int* in_sizes, int n_in,
                              void* d_out, int out_size, void* d_ws, size_t ws_size,
                              hipStream_t stream) {
    const float* adj = (const float*)d_in[0];        // (K, NK, NK) f32
    const int*   idx = (const int*)d_in[1];          // (K, NK) i32
    float*       out = (float*)d_out;                // (N, N) f32

    dim3 block(TPB, 1, 1);
    dim3 grid(N / R, 1, 1);                          // 512 blocks x 4 rows
    fia_fused<<<grid, block, 0, stream>>>(adj, idx, out);
}